// Round 1
// baseline (19.121 us; speedup 1.0000x reference)
//
#include <hip/hip_runtime.h>

// GuidedMoEBasic: B=16, D=64, H=768, NE=7, FEAT=776, 2*FEAT=1552
// Pairs per batch P = D*(D+1)/2 = 2080, N = 16*2080 = 33280.
//
// Key algebraic collapse: the expert MLP has no nonlinearity, so
//   o[e,n,:] = flat[n] @ (W1[e] @ W2[e]) + (b1[e] @ W2[e] + b2[e])
// and flat[n] = [conc[b,t], conc[b,end]], so everything reduces to
// per-utterance (1024 rows) precomputed 12-float vectors.

#define H_     768
#define NE_    7
#define FEAT_  776
#define TWOF   1552
#define NROW   1024
#define PAIRS  2080
#define NPAIR  33280
#define EXH    256

// workspace float layout
#define M_OFF  0        // 2*1552*2 = 6208 floats  (M[e][r][c])
#define BC_OFF 6208     // 4 floats                 (bconst[e][c])
#define PC_OFF 6212     // 1024*12 floats           (pc[row][j])

// ---------------------------------------------------------------------------
// Kernel 1: M[e][r][c] = sum_h W1[e][r][h] * W2[e][h][c]   (one wave per row)
//           bconst[e][c] = sum_h b1[e][h] * W2[e][h][c] + b2[e][c]
// ---------------------------------------------------------------------------
__global__ __launch_bounds__(256) void kM(const float* __restrict__ w1,
                                          const float* __restrict__ b1,
                                          const float* __restrict__ w2,
                                          const float* __restrict__ b2,
                                          float* __restrict__ M,
                                          float* __restrict__ bc) {
    const int lane = threadIdx.x & 63;
    const int wave = threadIdx.x >> 6;
    const int blk  = blockIdx.x;

    int e, r = 0;
    float4 a;
    if (blk < 776) {
        const int row = blk * 4 + wave;          // 0..3103
        e = row / TWOF;
        r = row - e * TWOF;
        a = ((const float4*)(w1 + ((size_t)e * TWOF + r) * EXH))[lane];
    } else {
        if (wave >= 2) return;                   // whole-wave uniform exit
        e = wave;
        a = ((const float4*)(b1 + e * EXH))[lane];
    }

    // W2[e] is [256][2]; lane covers h = lane*4 .. lane*4+3 -> 8 contiguous floats
    const float4* wv = (const float4*)(w2 + (size_t)e * EXH * 2);
    const float4 q0 = wv[lane * 2];
    const float4 q1 = wv[lane * 2 + 1];
    float a0 = a.x * q0.x + a.y * q0.z + a.z * q1.x + a.w * q1.z;
    float a1 = a.x * q0.y + a.y * q0.w + a.z * q1.y + a.w * q1.w;

#pragma unroll
    for (int off = 32; off; off >>= 1) {
        a0 += __shfl_down(a0, off);
        a1 += __shfl_down(a1, off);
    }
    if (lane == 0) {
        if (blk < 776) {
            M[((size_t)e * TWOF + r) * 2 + 0] = a0;
            M[((size_t)e * TWOF + r) * 2 + 1] = a1;
        } else {
            bc[e * 2 + 0] = a0 + b2[e * 2 + 0];
            bc[e * 2 + 1] = a1 + b2[e * 2 + 1];
        }
    }
}

// ---------------------------------------------------------------------------
// Kernel 2: one block per utterance row (1024 blocks).
//   emotion_pred[row] = pooled[row] @ emo_w + emo_b   (written to d_out)
//   conc[row] = [pooled, emotion, spk]  (in LDS)
//   pc[row][0..11] = conc[row] @ [M0_top, M1_top, M0_bot, M1_bot, gwA, gwB]
// ---------------------------------------------------------------------------
__global__ __launch_bounds__(256) void kRow(const float* __restrict__ pooled,
                                            const int* __restrict__ spk,
                                            const float* __restrict__ emo_w,
                                            const float* __restrict__ emo_b,
                                            const float* __restrict__ gate_w,
                                            const float* __restrict__ M,
                                            float* __restrict__ out_emo,
                                            float* __restrict__ pc) {
    __shared__ float conc[FEAT_];
    __shared__ float redE[4][NE_];
    __shared__ float redP[4][12];

    const int row  = blockIdx.x;
    const int t    = threadIdx.x;
    const int lane = t & 63;
    const int wave = t >> 6;
    const float* prow = pooled + (size_t)row * H_;

    // emotion head partials + stage pooled into LDS
    float acc[NE_] = {0.f, 0.f, 0.f, 0.f, 0.f, 0.f, 0.f};
    for (int i = t; i < H_; i += 256) {
        const float p = prow[i];
        conc[i] = p;
#pragma unroll
        for (int k = 0; k < NE_; k++) acc[k] += p * emo_w[i * NE_ + k];
    }
#pragma unroll
    for (int off = 32; off; off >>= 1)
#pragma unroll
        for (int k = 0; k < NE_; k++) acc[k] += __shfl_down(acc[k], off);
    if (lane == 0)
#pragma unroll
        for (int k = 0; k < NE_; k++) redE[wave][k] = acc[k];
    __syncthreads();

    if (t < NE_) {
        const float v = emo_b[t] + redE[0][t] + redE[1][t] + redE[2][t] + redE[3][t];
        out_emo[row * NE_ + t] = v;
        conc[H_ + t] = v;
    } else if (t == NE_) {
        conc[FEAT_ - 1] = (float)spk[row];
    }
    __syncthreads();

    // 12 projections of the conc row
    float pa[12] = {0.f, 0.f, 0.f, 0.f, 0.f, 0.f, 0.f, 0.f, 0.f, 0.f, 0.f, 0.f};
    for (int f = t; f < FEAT_; f += 256) {
        const float c = conc[f];
        const float* a0 = M + f * 2;                     // e0, W1 row f      (v1)
        const float* a1 = M + (TWOF + f) * 2;            // e1, W1 row f      (v1)
        const float* b0 = M + (FEAT_ + f) * 2;           // e0, W1 row 776+f  (v2)
        const float* b1 = M + (TWOF + FEAT_ + f) * 2;    // e1, W1 row 776+f  (v2)
        pa[0]  += c * a0[0];  pa[1]  += c * a0[1];
        pa[2]  += c * a1[0];  pa[3]  += c * a1[1];
        pa[4]  += c * b0[0];  pa[5]  += c * b0[1];
        pa[6]  += c * b1[0];  pa[7]  += c * b1[1];
        pa[8]  += c * gate_w[f * 2];              pa[9]  += c * gate_w[f * 2 + 1];
        pa[10] += c * gate_w[(FEAT_ + f) * 2];    pa[11] += c * gate_w[(FEAT_ + f) * 2 + 1];
    }
#pragma unroll
    for (int off = 32; off; off >>= 1)
#pragma unroll
        for (int k = 0; k < 12; k++) pa[k] += __shfl_down(pa[k], off);
    if (lane == 0)
#pragma unroll
        for (int k = 0; k < 12; k++) redP[wave][k] = pa[k];
    __syncthreads();

    if (t < 12)
        pc[row * 12 + t] = redP[0][t] + redP[1][t] + redP[2][t] + redP[3][t];
}

// ---------------------------------------------------------------------------
// Kernel 3: one thread per pair. O(1) work per pair from pc vectors.
// Pair p (end-major): end = row of tril, t = col, p = end*(end+1)/2 + t.
// ---------------------------------------------------------------------------
__global__ __launch_bounds__(256) void kPair(const float* __restrict__ pc,
                                             const float* __restrict__ bc,
                                             const float* __restrict__ gate_b,
                                             float* __restrict__ out_cause) {
    const int n = blockIdx.x * 256 + threadIdx.x;
    if (n >= NPAIR) return;
    const int b = n / PAIRS;
    const int p = n - b * PAIRS;

    int end = (int)((sqrtf(8.0f * (float)p + 1.0f) - 1.0f) * 0.5f);
    while ((end + 1) * (end + 2) / 2 <= p) end++;
    while (end * (end + 1) / 2 > p) end--;
    const int tt = p - end * (end + 1) / 2;

    const float* pt = pc + ((size_t)b * 64 + tt) * 12;   // first-half (t) row
    const float* pe = pc + ((size_t)b * 64 + end) * 12;  // second-half (end) row

    const float g0 = pt[8] + pe[10] + gate_b[0];
    const float g1 = pt[9] + pe[11] + gate_b[1];

    const float o00 = pt[0] + pe[4] + bc[0];   // e=0, c=0
    const float o01 = pt[1] + pe[5] + bc[1];   // e=0, c=1
    const float o10 = pt[2] + pe[6] + bc[2];   // e=1, c=0
    const float o11 = pt[3] + pe[7] + bc[3];   // e=1, c=1

    out_cause[(size_t)n * 2 + 0] = o00 * g0 + o10 * g1;
    out_cause[(size_t)n * 2 + 1] = o01 * g0 + o11 * g1;
}

// ---------------------------------------------------------------------------
extern "C" void kernel_launch(void* const* d_in, const int* in_sizes, int n_in,
                              void* d_out, int out_size, void* d_ws, size_t ws_size,
                              hipStream_t stream) {
    const float* pooled = (const float*)d_in[0];
    const int*   spk    = (const int*)d_in[1];
    const float* emo_w  = (const float*)d_in[2];
    const float* emo_b  = (const float*)d_in[3];
    const float* gate_w = (const float*)d_in[4];
    const float* gate_b = (const float*)d_in[5];
    const float* exp_w1 = (const float*)d_in[6];
    const float* exp_b1 = (const float*)d_in[7];
    const float* exp_w2 = (const float*)d_in[8];
    const float* exp_b2 = (const float*)d_in[9];

    float* out = (float*)d_out;                 // [1024*7] emotion | [33280*2] cause
    float* W   = (float*)d_ws;
    float* M   = W + M_OFF;
    float* bc  = W + BC_OFF;
    float* pc  = W + PC_OFF;

    hipLaunchKernelGGL(kM, dim3(777), dim3(256), 0, stream,
                       exp_w1, exp_b1, exp_w2, exp_b2, M, bc);
    hipLaunchKernelGGL(kRow, dim3(NROW), dim3(256), 0, stream,
                       pooled, spk, emo_w, emo_b, gate_w, M, out, pc);
    hipLaunchKernelGGL(kPair, dim3((NPAIR + 255) / 256), dim3(256), 0, stream,
                       pc, bc, gate_b, out + NROW * NE_);
}